// Round 5
// baseline (127655.811 us; speedup 1.0000x reference)
//
#include <hip/hip_runtime.h>
#include <stdint.h>
#include <math.h>

#define NN 1024
#define NB 16
#define NLOW 16
#define PNB 32      // panel width
#define GPB 16      // blocks per batch in persistent panel kernel
#define NTHR 256

// ---------------------------------------------------------------------------
// Sense-reversing barrier among the GPB blocks of one batch (device-scope).
__device__ inline void bbar(int* cnt, int* gen) {
    __syncthreads();
    if (threadIdx.x == 0) {
        __threadfence();
        int g0 = __hip_atomic_load(gen, __ATOMIC_ACQUIRE, __HIP_MEMORY_SCOPE_AGENT);
        int a = __hip_atomic_fetch_add(cnt, 1, __ATOMIC_ACQ_REL, __HIP_MEMORY_SCOPE_AGENT);
        if (a == GPB - 1) {
            __hip_atomic_store(cnt, 0, __ATOMIC_RELAXED, __HIP_MEMORY_SCOPE_AGENT);
            __hip_atomic_fetch_add(gen, 1, __ATOMIC_RELEASE, __HIP_MEMORY_SCOPE_AGENT);
        } else {
            while (__hip_atomic_load(gen, __ATOMIC_ACQUIRE, __HIP_MEMORY_SCOPE_AGENT) == g0) {
                __builtin_amdgcn_s_sleep(1);
            }
        }
        __threadfence();
    }
    __syncthreads();
}

// ---------------------------------------------------------------------------
__global__ void k_symmetrize(const float* A, float* M) {
    int64_t t = (int64_t)blockIdx.x * blockDim.x + threadIdx.x;
    if (t >= (int64_t)NB * NN * NN) return;
    int b = (int)(t / (NN * NN));
    int rc = (int)(t % (NN * NN));
    int r = rc / NN, c = rc % NN;
    if (r > c) return;
    const float* Ab = A + (int64_t)b * NN * NN;
    float s = 0.5f * (Ab[(int64_t)r * NN + c] + Ab[(int64_t)c * NN + r]);
    float* Mb = M + (int64_t)b * NN * NN;
    Mb[(int64_t)r * NN + c] = s;
    Mb[(int64_t)c * NN + r] = s;
}

__global__ void k_zerobars(int* bars) {
    int t = blockIdx.x * 256 + threadIdx.x;
    if (t < NB * 64) bars[t] = 0;
}

// ---------------------------------------------------------------------------
// Persistent panel kernel: handles all jmax columns of panel k0.
// Grid: NB*GPB blocks of 256 threads; block -> (b = blockIdx%NB, g = blockIdx/NB).
// Reflectors stored UNSCALED: u = [alpha-beta, x...], H = I - taut*u*u^T,
// taut = -1/(beta*(alpha-beta)).
__global__ __launch_bounds__(256) void k_panel_persist(
    float* M, float* Vp, float* Wp, float* wvpart,
    float* tauA, float* eA, float* dA, float* Urev, int useU,
    double* dotwA, double* dotwpart, double* norm2part,
    double* c1A, double* c2A, float* alphaA,
    int* bars, int k0, int jmax)
{
    int b = (int)(blockIdx.x % NB), g = (int)(blockIdx.x / NB);
    int tid = threadIdx.x;
    int m0 = NN - 1 - k0;
    float* Mb = M + (int64_t)b * NN * NN;
    float* VpB = Vp + (int64_t)b * PNB * NN;
    float* WpB = Wp + (int64_t)b * PNB * NN;
    float* wvp = wvpart + (int64_t)b * GPB * NN;
    int* cnt = bars + b * 64;
    int* gen = bars + b * 64 + 32;

    __shared__ float h1[PNB], h2[PNB], h3[PNB], g1s[PNB], g2s[PNB];
    __shared__ double sb[4];
    __shared__ double djp_sh;

    for (int j = 0; j <= jmax; ++j) {
        int k = k0 + j;
        // ---------------- phase 1: finalize W' col j-1, partial dotw ----------
        if (j > 0) {
            int jp = j - 1;
            if (tid < jp) {
                double kap = 0.5 * (double)tauA[b * NN + k0 + tid] * dotwA[b * NN + k0 + tid];
                double c2v = c2A[b * PNB + tid];
                g1s[tid] = (float)(c1A[b * PNB + tid] - 2.0 * kap * c2v);
                g2s[tid] = (float)c2v;
            }
            __syncthreads();
            float taut = tauA[b * NN + k0 + jp];
            const float* ujp = VpB + jp * NN;
            float* wcol = WpB + jp * NN;
            int i = jp + g * NTHR + tid;
            double dacc = 0.0;
            if (i < m0) {
                float wr = 0.f;
#pragma unroll
                for (int q = 0; q < GPB; ++q) wr += wvp[q * NN + (i - jp)];
                for (int t = 0; t < jp; ++t)
                    wr -= VpB[t * NN + i] * g1s[t] + WpB[t * NN + i] * g2s[t];
                float wf = taut * wr;
                wcol[i] = wf;
                dacc = (double)wf * (double)ujp[i];
            }
            for (int o = 32; o; o >>= 1) dacc += __shfl_xor(dacc, o);
            if ((tid & 63) == 0) sb[tid >> 6] = dacc;
            __syncthreads();
            if (tid == 0) dotwpart[b * GPB + g] = sb[0] + sb[1] + sb[2] + sb[3];
        }
        bbar(cnt, gen);
        if (j == jmax) {
            if (g == 0 && tid == 0 && jmax > 0) {
                double s = 0.0;
                for (int q = 0; q < GPB; ++q) s += dotwpart[b * GPB + q];
                dotwA[b * NN + k0 + jmax - 1] = s;
            }
            break;   // uniform across all blocks
        }
        // ---------------- phase 2: column update -> unscaled reflector --------
        if (tid == 0) {
            double s = 0.0;
            if (j > 0) for (int q = 0; q < GPB; ++q) s += dotwpart[b * GPB + q];
            djp_sh = s;
        }
        __syncthreads();
        if (tid < j) {
            double dw = (tid == j - 1) ? djp_sh : dotwA[b * NN + k0 + tid];
            float kap = (float)(0.5 * (double)tauA[b * NN + k0 + tid] * dw);
            float ur = VpB[tid * NN + (j - 1)];
            float wr = WpB[tid * NN + (j - 1)];
            float wbar = wr - kap * ur;
            h1[tid] = wbar - kap * ur;
            h2[tid] = ur;
            h3[tid] = ur * wbar;
        }
        __syncthreads();
        if (g == 0 && tid == 0 && j > 0) dotwA[b * NN + k0 + j - 1] = djp_sh;
        {
            int i = j + g * NTHR + tid;
            float x = 0.f;
            if (i < m0) {
                x = Mb[(int64_t)(k0 + 1 + i) * NN + k];
                for (int t = 0; t < j; ++t)
                    x -= VpB[t * NN + i] * h1[t] + WpB[t * NN + i] * h2[t];
                VpB[j * NN + i] = x;
                if (useU) Urev[((int64_t)b * NN + k) * NN + (i - j)] = x;
                else      Mb[(int64_t)(k0 + 1 + i) * NN + k] = x;
            }
            if (g == 0 && tid == 0) {
                alphaA[b] = x;
                float dk = Mb[(int64_t)k * NN + k];
                for (int t = 0; t < j; ++t) dk -= 2.f * h3[t];
                dA[b * NN + k] = dk;
            }
            double nacc = (i > j && i < m0) ? (double)x * (double)x : 0.0;
            for (int o = 32; o; o >>= 1) nacc += __shfl_xor(nacc, o);
            if ((tid & 63) == 0) sb[tid >> 6] = nacc;
            __syncthreads();
            if (tid == 0) norm2part[b * GPB + g] = sb[0] + sb[1] + sb[2] + sb[3];
        }
        bbar(cnt, gen);
        // ---------------- phase 3: scalars + symv partials + c1/c2 dots -------
        {
            double rest = 0.0;
            for (int q = 0; q < GPB; ++q) rest += norm2part[b * GPB + q];
            float alpha = alphaA[b];
            float albe, beta, taut;
            if (rest == 0.0) { albe = 0.f; beta = alpha; taut = 0.f; }
            else {
                double a = (double)alpha, nrm = sqrt(a * a + rest);
                double bt = (a >= 0.0) ? -nrm : nrm, ab = a - bt;
                albe = (float)ab; beta = (float)bt; taut = (float)(-1.0 / (bt * ab));
            }
            if (g == 0 && tid == 0) {
                tauA[b * NN + k] = taut;
                eA[b * NN + k] = beta;
                VpB[j * NN + j] = albe;
                if (useU) Urev[((int64_t)b * NN + k) * NN] = albe;
                else      Mb[(int64_t)(k0 + 1 + j) * NN + k] = albe;
            }
            int m = NN - 1 - k;
            const float* ucol = VpB + j * NN;
            int sl = (m + GPB - 1) / GPB;
            int j0 = g * sl, j1 = min(m, j0 + sl);
            float a0 = 0.f, a1 = 0.f, a2 = 0.f, a3 = 0.f;
            for (int jj = j0; jj < j1; ++jj) {
                float uj = (jj == 0) ? albe : ucol[j + jj];
                const float* row = Mb + (int64_t)(k + 1 + jj) * NN + (k + 1);
                int i0 = tid;
                if (i0 < m) a0 += row[i0] * uj;
                i0 += 256; if (i0 < m) a1 += row[i0] * uj;
                i0 += 256; if (i0 < m) a2 += row[i0] * uj;
                i0 += 256; if (i0 < m) a3 += row[i0] * uj;
            }
            float* wp = wvp + g * NN;
            if (tid < m) wp[tid] = a0;
            if (tid + 256 < m) wp[tid + 256] = a1;
            if (tid + 512 < m) wp[tid + 512] = a2;
            if (tid + 768 < m) wp[tid + 768] = a3;
            for (int t = g; t < j; t += GPB) {
                const float* ut = VpB + t * NN;
                const float* wt = WpB + t * NN;
                double d1 = 0.0, d2 = 0.0;
                for (int i2 = j + tid; i2 < m0; i2 += 256) {
                    float uj2 = (i2 == j) ? albe : ucol[i2];
                    d1 += (double)wt[i2] * (double)uj2;
                    d2 += (double)ut[i2] * (double)uj2;
                }
                for (int o = 32; o; o >>= 1) { d1 += __shfl_xor(d1, o); d2 += __shfl_xor(d2, o); }
                __syncthreads();
                if ((tid & 63) == 0) sb[tid >> 6] = d1;
                __syncthreads();
                if (tid == 0) c1A[b * PNB + t] = sb[0] + sb[1] + sb[2] + sb[3];
                __syncthreads();
                if ((tid & 63) == 0) sb[tid >> 6] = d2;
                __syncthreads();
                if (tid == 0) c2A[b * PNB + t] = sb[0] + sb[1] + sb[2] + sb[3];
                __syncthreads();
            }
        }
        bbar(cnt, gen);
    }
}

// ---------------------------------------------------------------------------
// Trailing update A(s:,s:) -= U*Wbar^T + Wbar*U^T with Wbar = w' - kappa*u.
__global__ __launch_bounds__(256) void k_update(float* M, const float* Vp, const float* Wp,
                                                const float* tauA, const double* dotwA,
                                                int k0, int nbe) {
    int b = blockIdx.x;
    int s = k0 + nbe, m2 = NN - s;
    int r0 = blockIdx.y * 64, c0 = blockIdx.z * 64;
    if (r0 >= m2 || c0 >= m2) return;
    __shared__ float Vr[PNB][64], Wr[PNB][64], Vc[PNB][64], Wc[PNB][64];
    __shared__ float kap[PNB];
    int tid = threadIdx.x;
    if (tid < nbe)
        kap[tid] = (float)(0.5 * (double)tauA[b * NN + k0 + tid] * dotwA[b * NN + k0 + tid]);
    __syncthreads();
    int rowoff = nbe - 1;
    for (int idx = tid; idx < nbe * 64; idx += 256) {
        int t = idx >> 6, x = idx & 63;
        const float* vp = Vp + ((int64_t)b * PNB + t) * NN;
        const float* wp = Wp + ((int64_t)b * PNB + t) * NN;
        int rr = r0 + x, cc = c0 + x;
        float vr = (rr < m2) ? vp[rowoff + rr] : 0.f;
        float wr = (rr < m2) ? wp[rowoff + rr] : 0.f;
        float vc = (cc < m2) ? vp[rowoff + cc] : 0.f;
        float wc = (cc < m2) ? wp[rowoff + cc] : 0.f;
        Vr[t][x] = vr; Wr[t][x] = wr - kap[t] * vr;
        Vc[t][x] = vc; Wc[t][x] = wc - kap[t] * vc;
    }
    __syncthreads();
    int tx = tid & 15, ty = tid >> 4;
    float accv[4][4] = {};
    for (int t = 0; t < nbe; ++t) {
        float va[4], wa[4], vb4[4], wb4[4];
#pragma unroll
        for (int a = 0; a < 4; ++a) {
            va[a] = Vr[t][ty * 4 + a]; wa[a] = Wr[t][ty * 4 + a];
            vb4[a] = Vc[t][tx * 4 + a]; wb4[a] = Wc[t][tx * 4 + a];
        }
#pragma unroll
        for (int a = 0; a < 4; ++a)
#pragma unroll
            for (int c = 0; c < 4; ++c) accv[a][c] += va[a] * wb4[c] + wa[a] * vb4[c];
    }
    float* Mb = M + (int64_t)b * NN * NN;
    for (int a = 0; a < 4; ++a) {
        int r = r0 + ty * 4 + a;
        if (r >= m2) break;
        for (int c = 0; c < 4; ++c) {
            int cc = c0 + tx * 4 + c;
            if (cc >= m2) continue;
            Mb[(int64_t)(s + r) * NN + (s + cc)] -= accv[a][c];
        }
    }
}

// ---------------------------------------------------------------------------
__global__ void k_extract2(const float* M, float* dA, float* eA) {
    int b = blockIdx.x;
    if (threadIdx.x == 0) {
        const float* Mb = M + (int64_t)b * NN * NN;
        dA[b * NN + NN - 2] = Mb[(int64_t)(NN - 2) * NN + NN - 2];
        dA[b * NN + NN - 1] = Mb[(int64_t)(NN - 1) * NN + NN - 1];
        eA[b * NN + NN - 2] = Mb[(int64_t)(NN - 1) * NN + NN - 2];
    }
}

// ---------------------------------------------------------------------------
__global__ void k_bisect(const float* dA, const float* eA, double* lam, float* out) {
    int p = blockIdx.x * 64 + threadIdx.x;
    if (p >= NB * NLOW) return;
    int b = p >> 4, j = p & 15;
    const float* d = dA + b * NN;
    const float* e = eA + b * NN;
    double lo = 1e30, hi = -1e30;
    for (int i = 0; i < NN; ++i) {
        double di = (double)d[i];
        double r = 0.0;
        if (i > 0) r += fabs((double)e[i - 1]);
        if (i < NN - 1) r += fabs((double)e[i]);
        lo = fmin(lo, di - r);
        hi = fmax(hi, di + r);
    }
    lo -= 1e-3; hi += 1e-3;
    for (int it = 0; it < 50; ++it) {
        double x = 0.5 * (lo + hi);
        int cntn = 0;
        double q = (double)d[0] - x;
        if (q < 0.0) cntn++;
        for (int i = 1; i < NN; ++i) {
            double ei = (double)e[i - 1];
            double den = q;
            if (fabs(den) < 1e-30) den = (den < 0.0) ? -1e-30 : 1e-30;
            q = ((double)d[i] - x) - ei * ei / den;
            if (q < 0.0) cntn++;
        }
        if (cntn >= j + 1) hi = x; else lo = x;
    }
    double l = 0.5 * (lo + hi);
    lam[p] = l;
    out[b * NLOW + j] = (float)l;
}

// ---------------------------------------------------------------------------
__global__ void k_invit(const float* dA, const float* eA, const double* lam,
                        float* vtri, double* U0, double* U1, double* U2,
                        double* LM, float* PV, double* XV) {
    int p = blockIdx.x * blockDim.x + threadIdx.x;
    if (p >= NB * NLOW) return;
    int b = p / NLOW;
    const float* d = dA + b * NN;
    const float* e = eA + b * NN;
    double lambda = lam[p];
    double* dd  = U0 + (int64_t)p * NN;
    double* du  = U1 + (int64_t)p * NN;
    double* du2 = U2 + (int64_t)p * NN;
    double* dl  = LM + (int64_t)p * NN;
    float*  pv  = PV + (int64_t)p * NN;
    double* X   = XV + (int64_t)p * NN;

    for (int i = 0; i < NN; ++i) dd[i] = (double)d[i] - lambda;
    for (int i = 0; i < NN - 1; ++i) { du[i] = (double)e[i]; dl[i] = (double)e[i]; }
    du[NN - 1] = 0.0; dl[NN - 1] = 0.0;

    for (int i = 0; i < NN - 1; ++i) {
        if (fabs(dd[i]) >= fabs(dl[i])) {
            pv[i] = 0.f;
            double fact = (dd[i] != 0.0) ? dl[i] / dd[i] : 0.0;
            dl[i] = fact;
            dd[i + 1] -= fact * du[i];
            du2[i] = 0.0;
        } else {
            pv[i] = 1.f;
            double fact = dd[i] / dl[i];
            dd[i] = dl[i];
            dl[i] = fact;
            double temp = du[i];
            du[i] = dd[i + 1];
            dd[i + 1] = temp - fact * dd[i + 1];
            if (i < NN - 2) { du2[i] = du[i + 1]; du[i + 1] = -fact * du[i + 1]; }
            else du2[i] = 0.0;
        }
    }
    for (int i = 0; i < NN; ++i)
        if (fabs(dd[i]) < 1e-300) dd[i] = (dd[i] < 0.0) ? -1e-300 : 1e-300;

    for (int i = 0; i < NN; ++i) {
        uint32_t h = ((uint32_t)i * 2654435761u) ^ ((uint32_t)p * 40503u);
        h = h * 1664525u + 1013904223u;
        X[i] = 1.0 + 1e-3 * ((double)(h & 2047) / 1024.0 - 1.0);
    }
    for (int iter = 0; iter < 2; ++iter) {
        for (int i = 0; i < NN - 1; ++i) {
            if (pv[i] == 0.f) X[i + 1] -= dl[i] * X[i];
            else { double t = X[i]; X[i] = X[i + 1]; X[i + 1] = t - dl[i] * X[i]; }
        }
        X[NN - 1] /= dd[NN - 1];
        X[NN - 2] = (X[NN - 2] - du[NN - 2] * X[NN - 1]) / dd[NN - 2];
        for (int i = NN - 3; i >= 0; --i)
            X[i] = (X[i] - du[i] * X[i + 1] - du2[i] * X[i + 2]) / dd[i];
        double nrm = 0.0;
        for (int i = 0; i < NN; ++i) nrm += X[i] * X[i];
        double inv = 1.0 / sqrt(fmax(nrm, 1e-300));
        for (int i = 0; i < NN; ++i) X[i] *= inv;
    }
    float* vt = vtri + (int64_t)p * NN;
    for (int i = 0; i < NN; ++i) vt[i] = (float)X[i];
}

// ---------------------------------------------------------------------------
__global__ void k_gs(float* vtri) {
    int b = blockIdx.x;
    float* V = vtri + (int64_t)b * NLOW * NN;
    __shared__ double red[256];
    for (int j = 0; j < NLOW; ++j) {
        float* vj = V + j * NN;
        for (int i2 = 0; i2 < j; ++i2) {
            const float* vi = V + i2 * NN;
            double acc = 0.0;
            for (int t = threadIdx.x; t < NN; t += 256) acc += (double)vi[t] * (double)vj[t];
            red[threadIdx.x] = acc; __syncthreads();
            for (int s = 128; s > 0; s >>= 1) {
                if ((int)threadIdx.x < s) red[threadIdx.x] += red[threadIdx.x + s];
                __syncthreads();
            }
            float r = (float)red[0];
            for (int t = threadIdx.x; t < NN; t += 256) vj[t] -= r * vi[t];
            __syncthreads();
        }
        double acc = 0.0;
        for (int t = threadIdx.x; t < NN; t += 256) acc += (double)vj[t] * (double)vj[t];
        red[threadIdx.x] = acc; __syncthreads();
        for (int s = 128; s > 0; s >>= 1) {
            if ((int)threadIdx.x < s) red[threadIdx.x] += red[threadIdx.x + s];
            __syncthreads();
        }
        float inv = (float)(1.0 / sqrt(fmax(red[0], 1e-300)));
        for (int t = threadIdx.x; t < NN; t += 256) vj[t] *= inv;
        __syncthreads();
    }
}

// ---------------------------------------------------------------------------
// Back-transform: H_k = I - taut_k * u_k u_k^T, applied k = NN-3 .. 0.
__global__ __launch_bounds__(512) void k_backtransform(const float* M, const float* Urev,
                                                       int useU, const float* tauA,
                                                       const float* vtri, float* out) {
    int b = blockIdx.x;
    int pass = blockIdx.y;
    int w = threadIdx.x >> 6;
    int lane = threadIdx.x & 63;
    int j = pass * 8 + w;
    __shared__ float xs[8][NN];
    __shared__ float us[NN];
    const float* Mb = M + (int64_t)b * NN * NN;
    for (int i = lane; i < NN; i += 64)
        xs[w][i] = vtri[((int64_t)b * NLOW + j) * NN + i];
    __syncthreads();
    for (int k = NN - 3; k >= 0; --k) {
        int m = NN - 1 - k;
        if (useU) {
            const float* ur = Urev + ((int64_t)b * NN + k) * NN;
            for (int t = threadIdx.x; t < (unsigned)m; t += 512) us[t] = ur[t];
        } else {
            for (int t = threadIdx.x; t < (unsigned)m; t += 512)
                us[t] = Mb[(int64_t)(k + 1 + t) * NN + k];
        }
        __syncthreads();
        float tauk = tauA[b * NN + k];
        float acc = 0.f;
        for (int t = lane; t < m; t += 64) acc += us[t] * xs[w][k + 1 + t];
        for (int off = 32; off > 0; off >>= 1) acc += __shfl_xor(acc, off);
        float s = tauk * acc;
        for (int t = lane; t < m; t += 64) xs[w][k + 1 + t] -= s * us[t];
        __syncthreads();
    }
    float mx = -1.f; int mi = 0;
    for (int i = lane; i < NN; i += 64) {
        float a = fabsf(xs[w][i]);
        if (a > mx) { mx = a; mi = i; }
    }
    for (int off = 32; off > 0; off >>= 1) {
        float omx = __shfl_xor(mx, off);
        int omi = __shfl_xor(mi, off);
        if (omx > mx || (omx == mx && omi < mi)) { mx = omx; mi = omi; }
    }
    float sgn = (xs[w][mi] < 0.f) ? -1.f : 1.f;
    for (int i = lane; i < NN; i += 64)
        out[256 + ((int64_t)(b * NN + i)) * NLOW + j] = sgn * xs[w][i];
}

// ---------------------------------------------------------------------------
extern "C" void kernel_launch(void* const* d_in, const int* in_sizes, int n_in,
                              void* d_out, int out_size, void* d_ws, size_t ws_size,
                              hipStream_t stream) {
    const float* A = (const float*)d_in[0];
    float* out = (float*)d_out;

    char* base = (char*)d_ws;
    size_t off = 0;
    auto alloc = [&](size_t bytes) -> void* {
        void* p = (void*)(base + off);
        off = (off + bytes + 255) & ~(size_t)255;
        return p;
    };
    double* lam  = (double*)alloc(sizeof(double) * NB * NLOW);
    double* u0   = (double*)alloc(sizeof(double) * (size_t)NB * NLOW * NN);
    double* u1   = (double*)alloc(sizeof(double) * (size_t)NB * NLOW * NN);
    double* u2   = (double*)alloc(sizeof(double) * (size_t)NB * NLOW * NN);
    double* lmul = (double*)alloc(sizeof(double) * (size_t)NB * NLOW * NN);
    double* xv   = (double*)alloc(sizeof(double) * (size_t)NB * NLOW * NN);
    float* pivf  = (float*)alloc(sizeof(float) * (size_t)NB * NLOW * NN);
    float* vtri  = (float*)alloc(sizeof(float) * (size_t)NB * NLOW * NN);
    float* tau   = (float*)alloc(sizeof(float) * NB * NN);
    float* evec  = (float*)alloc(sizeof(float) * NB * NN);
    float* dvec  = (float*)alloc(sizeof(float) * NB * NN);
    float* alphaA = (float*)alloc(sizeof(float) * NB);
    double* dotwA = (double*)alloc(sizeof(double) * NB * NN);
    double* dotwpart = (double*)alloc(sizeof(double) * NB * GPB);
    double* norm2part = (double*)alloc(sizeof(double) * NB * GPB);
    double* c1A   = (double*)alloc(sizeof(double) * NB * PNB);
    double* c2A   = (double*)alloc(sizeof(double) * NB * PNB);
    float* wvpart = (float*)alloc(sizeof(float) * (size_t)NB * GPB * NN);
    float* Vp    = (float*)alloc(sizeof(float) * (size_t)NB * PNB * NN);
    float* Wp    = (float*)alloc(sizeof(float) * (size_t)NB * PNB * NN);
    int* bars    = (int*)alloc(sizeof(int) * NB * 64);
    size_t small_end = off;
    size_t mat_bytes = sizeof(float) * (size_t)NB * NN * NN;

    float* M;
    if (ws_size >= small_end + mat_bytes)
        M = (float*)alloc(mat_bytes);
    else
        M = (float*)d_in[0];   // in-place fallback (harness restores d_in)

    float* Urev = nullptr;
    int useU = 0;
    if (ws_size >= off + mat_bytes) {
        Urev = (float*)alloc(mat_bytes);
        useU = 1;
    }

    int grid_sym = (NB * NN * NN) / 256;
    k_symmetrize<<<grid_sym, 256, 0, stream>>>(A, M);
    k_zerobars<<<4, 256, 0, stream>>>(bars);

    for (int k0 = 0; k0 < NN - 2; k0 += PNB) {
        int jmax = NN - 2 - k0; if (jmax > PNB) jmax = PNB;
        k_panel_persist<<<NB * GPB, NTHR, 0, stream>>>(M, Vp, Wp, wvpart, tau, evec, dvec,
                                                       Urev, useU, dotwA, dotwpart, norm2part,
                                                       c1A, c2A, alphaA, bars, k0, jmax);
        int s = k0 + jmax, m2 = NN - s;
        if (m2 > 0) {
            dim3 gu(NB, (unsigned)((m2 + 63) / 64), (unsigned)((m2 + 63) / 64));
            k_update<<<gu, 256, 0, stream>>>(M, Vp, Wp, tau, dotwA, k0, jmax);
        }
    }

    k_extract2<<<NB, 64, 0, stream>>>(M, dvec, evec);
    k_bisect<<<4, 64, 0, stream>>>(dvec, evec, lam, out);
    k_invit<<<4, 64, 0, stream>>>(dvec, evec, lam, vtri, u0, u1, u2, lmul, pivf, xv);
    k_gs<<<NB, 256, 0, stream>>>(vtri);
    dim3 gI(NB, 2);
    k_backtransform<<<gI, 512, 0, stream>>>(M, Urev, useU, tau, vtri, out);
}

// Round 7
// 59205.151 us; speedup vs baseline: 2.1562x; 2.1562x over previous
//
#include <hip/hip_runtime.h>
#include <stdint.h>
#include <math.h>

#define NN 1024
#define NB 16
#define NLOW 16
#define PNB 32      // panel width
#define JCH 256     // symv col-chunk
#define GMID 4      // blocks per batch for midAB

// ---------------------------------------------------------------------------
// Unscaled-reflector scalars from (alpha, norm2_rest):
//   beta = -sign(a)*sqrt(a^2+rest);  u0 = a - beta;  taut = -1/(beta*(a-beta))
__device__ inline void patchvals(float alphaf, double rest, float& albe, float& beta, float& taut) {
    if (rest == 0.0) { albe = 0.f; beta = alphaf; taut = 0.f; return; }
    double a = (double)alphaf;
    double nrm = sqrt(a * a + rest);
    double b = (a >= 0.0) ? -nrm : nrm;
    double ab = a - b;
    albe = (float)ab;
    beta = (float)b;
    taut = (float)(-1.0 / (b * ab));
}

// ---------------------------------------------------------------------------
__global__ void k_symmetrize(const float* A, float* M) {
    int64_t t = (int64_t)blockIdx.x * blockDim.x + threadIdx.x;
    if (t >= (int64_t)NB * NN * NN) return;
    int b = (int)(t / (NN * NN));
    int rc = (int)(t % (NN * NN));
    int r = rc / NN, c = rc % NN;
    if (r > c) return;
    const float* Ab = A + (int64_t)b * NN * NN;
    float s = 0.5f * (Ab[(int64_t)r * NN + c] + Ab[(int64_t)c * NN + r]);
    float* Mb = M + (int64_t)b * NN * NN;
    Mb[(int64_t)r * NN + c] = s;
    Mb[(int64_t)c * NN + r] = s;
}

__global__ void k_zeroinit(float* wv, double* norm2A, double* qA, double* dotwA) {
    int t = blockIdx.x * 256 + threadIdx.x;
    if (t < NB * NN) { wv[t] = 0.f; norm2A[t] = 0.0; qA[t] = 0.0; dotwA[t] = 0.0; }
}

// ---------------------------------------------------------------------------
// Fused per-column kernel, grid (NB, GMID) x 256 threads.
//  j>0: finalize W'_{j-1}[i] = taut*(wraw[i] - sum_{t<j-1}(u_t g1 + w'_t g2)),
//       dotw_{j-1} from the analytic scalar formula (no cross-block reduction):
//       dotw = taut*( q - sum_t(2 c1 c2 - 2 kap c2^2) ).
//  do_col: column update with j finished pairs -> unscaled reflector u_j,
//       alpha, norm2 (atomic). Scalars beta/taut finalized by the next k_symv.
// wv slot jp is read by ALL blocks (h-coeffs) -> skip zeroing it; stale slots
// [0,jmax) are zeroed by the finalize (do_col=0) call.
__global__ __launch_bounds__(256) void k_midAB(
    float* M, float* Vp, float* Wp, float* wv,
    float* tauA, float* dA, double* dotwA, const double* qA,
    const double* c1A, const double* c2A,
    double* norm2A, float* alphaA, float* Urev, int useU,
    int k0, int j, int do_col)
{
    int b = blockIdx.x, g = blockIdx.y, tid = threadIdx.x;
    int m0 = NN - 1 - k0;
    int k = k0 + j, jp = j - 1;
    float* Mb = M + (int64_t)b * NN * NN;
    float* VpB = Vp + (int64_t)b * PNB * NN;
    float* WpB = Wp + (int64_t)b * PNB * NN;
    __shared__ float skap[PNB], sg1[PNB], sg2[PNB];
    __shared__ double sc1d[PNB], sc2d[PNB];
    __shared__ float h1[PNB], h2[PNB], h3[PNB];

    int base = (j > 0) ? jp : 0;
    int i = base + g * 256 + tid;
    double dotw = 0.0;
    float taut = 0.f;

    if (j > 0) {
        if (tid < jp) {
            double kap = 0.5 * (double)tauA[b * NN + k0 + tid] * dotwA[b * NN + k0 + tid];
            double c1v = c1A[b * PNB + tid], c2v = c2A[b * PNB + tid];
            skap[tid] = (float)kap;
            sg1[tid] = (float)(c1v - 2.0 * kap * c2v);
            sg2[tid] = (float)c2v;
            sc1d[tid] = c1v; sc2d[tid] = c2v;
        }
        __syncthreads();
        taut = tauA[b * NN + k0 + jp];
        // analytic dotw (redundant per thread)
        {
            double s = 0.0;
            for (int t = 0; t < jp; ++t)
                s += 2.0 * sc1d[t] * sc2d[t] - 2.0 * (double)skap[t] * sc2d[t] * sc2d[t];
            dotw = (double)taut * (qA[b * NN + k0 + jp] - s);
        }
        // W' finalize on own element (skip zeroing slot jp: shared read target)
        if (i < m0) {
            float wr = wv[b * NN + i];
            if (i != jp) wv[b * NN + i] = 0.f;
            for (int t = 0; t < jp; ++t)
                wr -= VpB[t * NN + i] * sg1[t] + WpB[t * NN + i] * sg2[t];
            WpB[jp * NN + i] = taut * wr;
        }
        if (g == 0 && tid == 0) dotwA[b * NN + k0 + jp] = dotw;
    }

    if (!do_col) {
        __syncthreads();
        for (int z = g * 256 + tid; z <= jp; z += GMID * 256) wv[b * NN + z] = 0.f;
        return;
    }

    // h coefficients for t <= jp (row r = jp of the panel)
    if (j > 0 && tid <= jp) {
        int r = jp;
        float ur = VpB[tid * NN + r];
        float wpr, kapt;
        if (tid < jp) { wpr = WpB[tid * NN + r]; kapt = skap[tid]; }
        else {
            float wr = wv[b * NN + jp];
            for (int t = 0; t < jp; ++t)
                wr -= VpB[t * NN + r] * sg1[t] + WpB[t * NN + r] * sg2[t];
            wpr = taut * wr;
            kapt = (float)(0.5 * (double)taut * dotw);
        }
        float wbar = wpr - kapt * ur;
        h1[tid] = wbar - kapt * ur;
        h2[tid] = ur;
        h3[tid] = ur * wbar;
    }
    __syncthreads();

    // column update -> unscaled reflector u_j
    float x = 0.f;
    if (i >= j && i < m0) {
        x = Mb[(int64_t)(k0 + 1 + i) * NN + k];
        for (int t = 0; t < j; ++t)
            x -= VpB[t * NN + i] * h1[t] + WpB[t * NN + i] * h2[t];
        VpB[j * NN + i] = x;
        if (useU) Urev[((int64_t)b * NN + k) * NN + (i - j)] = x;
        else      Mb[(int64_t)(k0 + 1 + i) * NN + k] = x;
        if (i == j) alphaA[b] = x;
    }
    if (g == 0 && tid == 0) {
        float dk = Mb[(int64_t)k * NN + k];
        for (int t = 0; t < j; ++t) dk -= 2.f * h3[t];
        dA[b * NN + k] = dk;
    }
    double nacc = (i > j && i < m0) ? (double)x * (double)x : 0.0;
    for (int o = 32; o; o >>= 1) nacc += __shfl_xor(nacc, o);
    if ((tid & 63) == 0) atomicAdd(&norm2A[b * NN + k], nacc);
}

// ---------------------------------------------------------------------------
// symv(j): finalize reflector scalars (patch), wraw += A(k+1:,k+1:)*u_j,
// q = u^T A u (atomic), and extra y-blocks: c1[t]=w'_t^T u, c2[t]=u_t^T u.
__global__ __launch_bounds__(256) void k_symv(float* M, float* Vp, const float* Wp,
                                              float* wv, float* tauA, float* eA,
                                              const float* alphaA, const double* norm2A,
                                              double* qA, double* c1A, double* c2A,
                                              float* Urev, int useU,
                                              int k0, int j, int nr, int nc) {
    int b = blockIdx.x, y = blockIdx.y, tid = threadIdx.x;
    int k = k0 + j, m = NN - 1 - k, base = k + 1, m0 = NN - 1 - k0;
    float albe, beta, taut;
    patchvals(alphaA[b], norm2A[b * NN + k], albe, beta, taut);
    float* Mb = M + (int64_t)b * NN * NN;
    float* ucol = Vp + ((int64_t)b * PNB + j) * NN;
    __shared__ float vs[JCH];
    __shared__ double r1[256], r2[256];
    if (y < nr * nc) {
        if (y == 0 && tid == 0) {
            ucol[j] = albe;
            if (useU) Urev[((int64_t)b * NN + k) * NN] = albe;
            else      Mb[(int64_t)(k0 + 1 + j) * NN + k] = albe;
            eA[b * NN + k] = beta;
            tauA[b * NN + k] = taut;
        }
        int ir = y % nr, ic = y / nr;
        int i = ir * 256 + tid;
        int jg0 = ic * JCH, jg1 = min(m, jg0 + JCH);
        for (int t = tid; t < jg1 - jg0; t += 256) vs[t] = ucol[jg0 + t + j];
        __syncthreads();
        if (tid == 0 && jg0 == 0) vs[0] = albe;
        __syncthreads();
        double qp = 0.0;
        if (i < m) {
            const float* p = Mb + (int64_t)(base + jg0) * NN + base + i;
            float acc = 0.f;
            for (int jg = jg0; jg < jg1; ++jg, p += NN) acc += (*p) * vs[jg - jg0];
            atomicAdd(&wv[b * NN + i + j], acc);
            float urow = (i == 0) ? albe : ucol[j + i];
            qp = (double)acc * (double)urow;
        }
        for (int o = 32; o; o >>= 1) qp += __shfl_xor(qp, o);
        if ((tid & 63) == 0) atomicAdd(&qA[b * NN + k], qp);
    } else {
        int t = y - nr * nc;   // t < j
        const float* ut = Vp + ((int64_t)b * PNB + t) * NN;
        const float* wt = Wp + ((int64_t)b * PNB + t) * NN;
        double a1 = 0.0, a2 = 0.0;
        for (int i2 = j + tid; i2 < m0; i2 += 256) {
            float uj = (i2 == j) ? albe : ucol[i2];
            a1 += (double)wt[i2] * (double)uj;
            a2 += (double)ut[i2] * (double)uj;
        }
        r1[tid] = a1; r2[tid] = a2; __syncthreads();
        for (int s = 128; s > 0; s >>= 1) {
            if (tid < s) { r1[tid] += r1[tid + s]; r2[tid] += r2[tid + s]; }
            __syncthreads();
        }
        if (tid == 0) { c1A[b * PNB + t] = r1[0]; c2A[b * PNB + t] = r2[0]; }
    }
}

// ---------------------------------------------------------------------------
// Trailing update A(s:,s:) -= U*Wbar^T + Wbar*U^T with Wbar = w' - kappa*u.
__global__ __launch_bounds__(256) void k_update(float* M, const float* Vp, const float* Wp,
                                                const float* tauA, const double* dotwA,
                                                int k0, int nbe) {
    int b = blockIdx.x;
    int s = k0 + nbe, m2 = NN - s;
    int r0 = blockIdx.y * 64, c0 = blockIdx.z * 64;
    if (r0 >= m2 || c0 >= m2) return;
    __shared__ float Vr[PNB][64], Wr[PNB][64], Vc[PNB][64], Wc[PNB][64];
    __shared__ float kap[PNB];
    int tid = threadIdx.x;
    if (tid < nbe)
        kap[tid] = (float)(0.5 * (double)tauA[b * NN + k0 + tid] * dotwA[b * NN + k0 + tid]);
    __syncthreads();
    int rowoff = nbe - 1;
    for (int idx = tid; idx < nbe * 64; idx += 256) {
        int t = idx >> 6, x = idx & 63;
        const float* vp = Vp + ((int64_t)b * PNB + t) * NN;
        const float* wp = Wp + ((int64_t)b * PNB + t) * NN;
        int rr = r0 + x, cc = c0 + x;
        float vr = (rr < m2) ? vp[rowoff + rr] : 0.f;
        float wr = (rr < m2) ? wp[rowoff + rr] : 0.f;
        float vc = (cc < m2) ? vp[rowoff + cc] : 0.f;
        float wc = (cc < m2) ? wp[rowoff + cc] : 0.f;
        Vr[t][x] = vr; Wr[t][x] = wr - kap[t] * vr;
        Vc[t][x] = vc; Wc[t][x] = wc - kap[t] * vc;
    }
    __syncthreads();
    int tx = tid & 15, ty = tid >> 4;
    float accv[4][4] = {};
    for (int t = 0; t < nbe; ++t) {
        float va[4], wa[4], vb4[4], wb4[4];
#pragma unroll
        for (int a = 0; a < 4; ++a) {
            va[a] = Vr[t][ty * 4 + a]; wa[a] = Wr[t][ty * 4 + a];
            vb4[a] = Vc[t][tx * 4 + a]; wb4[a] = Wc[t][tx * 4 + a];
        }
#pragma unroll
        for (int a = 0; a < 4; ++a)
#pragma unroll
            for (int c = 0; c < 4; ++c) accv[a][c] += va[a] * wb4[c] + wa[a] * vb4[c];
    }
    float* Mb = M + (int64_t)b * NN * NN;
    for (int a = 0; a < 4; ++a) {
        int r = r0 + ty * 4 + a;
        if (r >= m2) break;
        for (int c = 0; c < 4; ++c) {
            int cc = c0 + tx * 4 + c;
            if (cc >= m2) continue;
            Mb[(int64_t)(s + r) * NN + (s + cc)] -= accv[a][c];
        }
    }
}

// ---------------------------------------------------------------------------
__global__ void k_extract2(const float* M, float* dA, float* eA) {
    int b = blockIdx.x;
    if (threadIdx.x == 0) {
        const float* Mb = M + (int64_t)b * NN * NN;
        dA[b * NN + NN - 2] = Mb[(int64_t)(NN - 2) * NN + NN - 2];
        dA[b * NN + NN - 1] = Mb[(int64_t)(NN - 1) * NN + NN - 1];
        eA[b * NN + NN - 2] = Mb[(int64_t)(NN - 1) * NN + NN - 2];
    }
}

// ---------------------------------------------------------------------------
__global__ void k_bisect(const float* dA, const float* eA, double* lam, float* out) {
    int p = blockIdx.x * 64 + threadIdx.x;
    if (p >= NB * NLOW) return;
    int b = p >> 4, j = p & 15;
    const float* d = dA + b * NN;
    const float* e = eA + b * NN;
    double lo = 1e30, hi = -1e30;
    for (int i = 0; i < NN; ++i) {
        double di = (double)d[i];
        double r = 0.0;
        if (i > 0) r += fabs((double)e[i - 1]);
        if (i < NN - 1) r += fabs((double)e[i]);
        lo = fmin(lo, di - r);
        hi = fmax(hi, di + r);
    }
    lo -= 1e-3; hi += 1e-3;
    for (int it = 0; it < 50; ++it) {
        double x = 0.5 * (lo + hi);
        int cntn = 0;
        double q = (double)d[0] - x;
        if (q < 0.0) cntn++;
        for (int i = 1; i < NN; ++i) {
            double ei = (double)e[i - 1];
            double den = q;
            if (fabs(den) < 1e-30) den = (den < 0.0) ? -1e-30 : 1e-30;
            q = ((double)d[i] - x) - ei * ei / den;
            if (q < 0.0) cntn++;
        }
        if (cntn >= j + 1) hi = x; else lo = x;
    }
    double l = 0.5 * (lo + hi);
    lam[p] = l;
    out[b * NLOW + j] = (float)l;
}

// ---------------------------------------------------------------------------
__global__ void k_invit(const float* dA, const float* eA, const double* lam,
                        float* vtri, double* U0, double* U1, double* U2,
                        double* LM, float* PV, double* XV) {
    int p = blockIdx.x * blockDim.x + threadIdx.x;
    if (p >= NB * NLOW) return;
    int b = p / NLOW;
    const float* d = dA + b * NN;
    const float* e = eA + b * NN;
    double lambda = lam[p];
    double* dd  = U0 + (int64_t)p * NN;
    double* du  = U1 + (int64_t)p * NN;
    double* du2 = U2 + (int64_t)p * NN;
    double* dl  = LM + (int64_t)p * NN;
    float*  pv  = PV + (int64_t)p * NN;
    double* X   = XV + (int64_t)p * NN;

    for (int i = 0; i < NN; ++i) dd[i] = (double)d[i] - lambda;
    for (int i = 0; i < NN - 1; ++i) { du[i] = (double)e[i]; dl[i] = (double)e[i]; }
    du[NN - 1] = 0.0; dl[NN - 1] = 0.0;

    for (int i = 0; i < NN - 1; ++i) {
        if (fabs(dd[i]) >= fabs(dl[i])) {
            pv[i] = 0.f;
            double fact = (dd[i] != 0.0) ? dl[i] / dd[i] : 0.0;
            dl[i] = fact;
            dd[i + 1] -= fact * du[i];
            du2[i] = 0.0;
        } else {
            pv[i] = 1.f;
            double fact = dd[i] / dl[i];
            dd[i] = dl[i];
            dl[i] = fact;
            double temp = du[i];
            du[i] = dd[i + 1];
            dd[i + 1] = temp - fact * dd[i + 1];
            if (i < NN - 2) { du2[i] = du[i + 1]; du[i + 1] = -fact * du[i + 1]; }
            else du2[i] = 0.0;
        }
    }
    for (int i = 0; i < NN; ++i)
        if (fabs(dd[i]) < 1e-300) dd[i] = (dd[i] < 0.0) ? -1e-300 : 1e-300;

    for (int i = 0; i < NN; ++i) {
        uint32_t h = ((uint32_t)i * 2654435761u) ^ ((uint32_t)p * 40503u);
        h = h * 1664525u + 1013904223u;
        X[i] = 1.0 + 1e-3 * ((double)(h & 2047) / 1024.0 - 1.0);
    }
    for (int iter = 0; iter < 2; ++iter) {
        for (int i = 0; i < NN - 1; ++i) {
            if (pv[i] == 0.f) X[i + 1] -= dl[i] * X[i];
            else { double t = X[i]; X[i] = X[i + 1]; X[i + 1] = t - dl[i] * X[i]; }
        }
        X[NN - 1] /= dd[NN - 1];
        X[NN - 2] = (X[NN - 2] - du[NN - 2] * X[NN - 1]) / dd[NN - 2];
        for (int i = NN - 3; i >= 0; --i)
            X[i] = (X[i] - du[i] * X[i + 1] - du2[i] * X[i + 2]) / dd[i];
        double nrm = 0.0;
        for (int i = 0; i < NN; ++i) nrm += X[i] * X[i];
        double inv = 1.0 / sqrt(fmax(nrm, 1e-300));
        for (int i = 0; i < NN; ++i) X[i] *= inv;
    }
    float* vt = vtri + (int64_t)p * NN;
    for (int i = 0; i < NN; ++i) vt[i] = (float)X[i];
}

// ---------------------------------------------------------------------------
__global__ void k_gs(float* vtri) {
    int b = blockIdx.x;
    float* V = vtri + (int64_t)b * NLOW * NN;
    __shared__ double red[256];
    for (int j = 0; j < NLOW; ++j) {
        float* vj = V + j * NN;
        for (int i2 = 0; i2 < j; ++i2) {
            const float* vi = V + i2 * NN;
            double acc = 0.0;
            for (int t = threadIdx.x; t < NN; t += 256) acc += (double)vi[t] * (double)vj[t];
            red[threadIdx.x] = acc; __syncthreads();
            for (int s = 128; s > 0; s >>= 1) {
                if ((int)threadIdx.x < s) red[threadIdx.x] += red[threadIdx.x + s];
                __syncthreads();
            }
            float r = (float)red[0];
            for (int t = threadIdx.x; t < NN; t += 256) vj[t] -= r * vi[t];
            __syncthreads();
        }
        double acc = 0.0;
        for (int t = threadIdx.x; t < NN; t += 256) acc += (double)vj[t] * (double)vj[t];
        red[threadIdx.x] = acc; __syncthreads();
        for (int s = 128; s > 0; s >>= 1) {
            if ((int)threadIdx.x < s) red[threadIdx.x] += red[threadIdx.x + s];
            __syncthreads();
        }
        float inv = (float)(1.0 / sqrt(fmax(red[0], 1e-300)));
        for (int t = threadIdx.x; t < NN; t += 256) vj[t] *= inv;
        __syncthreads();
    }
}

// ---------------------------------------------------------------------------
// Back-transform: H_k = I - taut_k * u_k u_k^T, applied k = NN-3 .. 0.
__global__ __launch_bounds__(512) void k_backtransform(const float* M, const float* Urev,
                                                       int useU, const float* tauA,
                                                       const float* vtri, float* out) {
    int b = blockIdx.x;
    int pass = blockIdx.y;
    int w = threadIdx.x >> 6;
    int lane = threadIdx.x & 63;
    int j = pass * 8 + w;
    __shared__ float xs[8][NN];
    __shared__ float us[NN];
    const float* Mb = M + (int64_t)b * NN * NN;
    for (int i = lane; i < NN; i += 64)
        xs[w][i] = vtri[((int64_t)b * NLOW + j) * NN + i];
    __syncthreads();
    for (int k = NN - 3; k >= 0; --k) {
        int m = NN - 1 - k;
        if (useU) {
            const float* ur = Urev + ((int64_t)b * NN + k) * NN;
            for (int t = threadIdx.x; t < (unsigned)m; t += 512) us[t] = ur[t];
        } else {
            for (int t = threadIdx.x; t < (unsigned)m; t += 512)
                us[t] = Mb[(int64_t)(k + 1 + t) * NN + k];
        }
        __syncthreads();
        float tauk = tauA[b * NN + k];
        float acc = 0.f;
        for (int t = lane; t < m; t += 64) acc += us[t] * xs[w][k + 1 + t];
        for (int off = 32; off > 0; off >>= 1) acc += __shfl_xor(acc, off);
        float s = tauk * acc;
        for (int t = lane; t < m; t += 64) xs[w][k + 1 + t] -= s * us[t];
        __syncthreads();
    }
    float mx = -1.f; int mi = 0;
    for (int i = lane; i < NN; i += 64) {
        float a = fabsf(xs[w][i]);
        if (a > mx) { mx = a; mi = i; }
    }
    for (int off = 32; off > 0; off >>= 1) {
        float omx = __shfl_xor(mx, off);
        int omi = __shfl_xor(mi, off);
        if (omx > mx || (omx == mx && omi < mi)) { mx = omx; mi = omi; }
    }
    float sgn = (xs[w][mi] < 0.f) ? -1.f : 1.f;
    for (int i = lane; i < NN; i += 64)
        out[256 + ((int64_t)(b * NN + i)) * NLOW + j] = sgn * xs[w][i];
}

// ---------------------------------------------------------------------------
extern "C" void kernel_launch(void* const* d_in, const int* in_sizes, int n_in,
                              void* d_out, int out_size, void* d_ws, size_t ws_size,
                              hipStream_t stream) {
    const float* A = (const float*)d_in[0];
    float* out = (float*)d_out;

    char* base = (char*)d_ws;
    size_t off = 0;
    auto alloc = [&](size_t bytes) -> void* {
        void* p = (void*)(base + off);
        off = (off + bytes + 255) & ~(size_t)255;
        return p;
    };
    double* lam  = (double*)alloc(sizeof(double) * NB * NLOW);
    double* u0   = (double*)alloc(sizeof(double) * (size_t)NB * NLOW * NN);
    double* u1   = (double*)alloc(sizeof(double) * (size_t)NB * NLOW * NN);
    double* u2   = (double*)alloc(sizeof(double) * (size_t)NB * NLOW * NN);
    double* lmul = (double*)alloc(sizeof(double) * (size_t)NB * NLOW * NN);
    double* xv   = (double*)alloc(sizeof(double) * (size_t)NB * NLOW * NN);
    float* pivf  = (float*)alloc(sizeof(float) * (size_t)NB * NLOW * NN);
    float* vtri  = (float*)alloc(sizeof(float) * (size_t)NB * NLOW * NN);
    float* tau   = (float*)alloc(sizeof(float) * NB * NN);
    float* evec  = (float*)alloc(sizeof(float) * NB * NN);
    float* dvec  = (float*)alloc(sizeof(float) * NB * NN);
    float* wv    = (float*)alloc(sizeof(float) * NB * NN);
    float* alphaA = (float*)alloc(sizeof(float) * NB);
    double* norm2A = (double*)alloc(sizeof(double) * NB * NN);
    double* qA     = (double*)alloc(sizeof(double) * NB * NN);
    double* dotwA  = (double*)alloc(sizeof(double) * NB * NN);
    double* c1A    = (double*)alloc(sizeof(double) * NB * PNB);
    double* c2A    = (double*)alloc(sizeof(double) * NB * PNB);
    float* Vp    = (float*)alloc(sizeof(float) * (size_t)NB * PNB * NN);
    float* Wp    = (float*)alloc(sizeof(float) * (size_t)NB * PNB * NN);
    size_t small_end = off;
    size_t mat_bytes = sizeof(float) * (size_t)NB * NN * NN;

    float* M;
    if (ws_size >= small_end + mat_bytes)
        M = (float*)alloc(mat_bytes);
    else
        M = (float*)d_in[0];   // in-place fallback (harness restores d_in)

    float* Urev = nullptr;
    int useU = 0;
    if (ws_size >= off + mat_bytes) {
        Urev = (float*)alloc(mat_bytes);
        useU = 1;
    }

    int grid_sym = (NB * NN * NN) / 256;
    k_symmetrize<<<grid_sym, 256, 0, stream>>>(A, M);
    k_zeroinit<<<(NB * NN + 255) / 256, 256, 0, stream>>>(wv, norm2A, qA, dotwA);

    for (int k0 = 0; k0 < NN - 2; k0 += PNB) {
        int jmax = NN - 2 - k0; if (jmax > PNB) jmax = PNB;
        for (int j = 0; j < jmax; ++j) {
            k_midAB<<<dim3(NB, GMID), 256, 0, stream>>>(M, Vp, Wp, wv, tau, dvec,
                                                        dotwA, qA, c1A, c2A, norm2A,
                                                        alphaA, Urev, useU, k0, j, 1);
            int k = k0 + j, m = NN - 1 - k;
            int nr = (m + 255) / 256, nc = (m + JCH - 1) / JCH;
            k_symv<<<dim3(NB, nr * nc + j), 256, 0, stream>>>(M, Vp, Wp, wv, tau, evec,
                                                              alphaA, norm2A, qA, c1A, c2A,
                                                              Urev, useU, k0, j, nr, nc);
        }
        k_midAB<<<dim3(NB, GMID), 256, 0, stream>>>(M, Vp, Wp, wv, tau, dvec,
                                                    dotwA, qA, c1A, c2A, norm2A,
                                                    alphaA, Urev, useU, k0, jmax, 0);
        int s = k0 + jmax, m2 = NN - s;
        if (m2 > 0) {
            dim3 gu(NB, (unsigned)((m2 + 63) / 64), (unsigned)((m2 + 63) / 64));
            k_update<<<gu, 256, 0, stream>>>(M, Vp, Wp, tau, dotwA, k0, jmax);
        }
    }

    k_extract2<<<NB, 64, 0, stream>>>(M, dvec, evec);
    k_bisect<<<4, 64, 0, stream>>>(dvec, evec, lam, out);
    k_invit<<<4, 64, 0, stream>>>(dvec, evec, lam, vtri, u0, u1, u2, lmul, pivf, xv);
    k_gs<<<NB, 256, 0, stream>>>(vtri);
    dim3 gI(NB, 2);
    k_backtransform<<<gI, 512, 0, stream>>>(M, Urev, useU, tau, vtri, out);
}